// Round 1
// baseline (196.190 us; speedup 1.0000x reference)
//
#include <hip/hip_runtime.h>
#include <hip/hip_bf16.h>
#include <stdint.h>

#define ALPHA 0.2f
#define NEG_INF -9000000000000000.0f

typedef __attribute__((ext_vector_type(8))) short short8;
typedef __attribute__((ext_vector_type(4))) float f32x4;

__device__ inline short f2bf(float x) {
    union { __hip_bfloat16 b; short s; } u;
    u.b = __float2bfloat16(x);
    return u.s;
}

// ---------------- Kernel A: Wh = h@W (fp32), store WhT bf16 [b][o][n]; f1,f2 fp32 ----------
__global__ __launch_bounds__(256) void kA(const float* __restrict__ h,
                                          const float* __restrict__ W,
                                          const float* __restrict__ av,
                                          short* __restrict__ whT,
                                          float* __restrict__ f1g,
                                          float* __restrict__ f2g) {
    int blk = blockIdx.x;
    int b  = blk >> 6;            // 8 batches
    int n0 = (blk & 63) * 32;     // 64 row-tiles of 32
    __shared__ float hlds[32 * 128];
    __shared__ float whlds[32 * 130];
    __shared__ float plds[32 * 8 * 2];
    int t = threadIdx.x;

    // stage h tile (32x128 fp32) coalesced
    const float4* hsrc = reinterpret_cast<const float4*>(h + ((size_t)(b * 2048 + n0)) * 128);
    float4* hl4 = reinterpret_cast<float4*>(hlds);
    #pragma unroll
    for (int k = 0; k < 4; k++) hl4[t + k * 256] = hsrc[t + k * 256];
    __syncthreads();

    int o  = t & 127;
    int rg = t >> 7;  // 0..1 -> rows rg*16..rg*16+15
    float acc[16];
    #pragma unroll
    for (int r = 0; r < 16; r++) acc[r] = 0.f;
    for (int f = 0; f < 128; f++) {
        float wv = W[f * 128 + o];
        #pragma unroll
        for (int r = 0; r < 16; r++)
            acc[r] += hlds[(rg * 16 + r) * 128 + f] * wv;
    }

    // store WhT bf16: thread holds 16 consecutive n for fixed o -> 32B contiguous
    {
        short8 lo, hi;
        #pragma unroll
        for (int r = 0; r < 8; r++)  lo[r] = f2bf(acc[r]);
        #pragma unroll
        for (int r = 0; r < 8; r++)  hi[r] = f2bf(acc[r + 8]);
        size_t base = ((size_t)(b * 128 + o)) * 2048 + n0 + rg * 16;
        *reinterpret_cast<short8*>(whT + base)     = lo;
        *reinterpret_cast<short8*>(whT + base + 8) = hi;
    }

    // wh to LDS for f1/f2 reduction
    #pragma unroll
    for (int r = 0; r < 16; r++) whlds[(rg * 16 + r) * 130 + o] = acc[r];
    __syncthreads();

    {
        int r = t & 31, og = t >> 5;  // og 0..7
        float s1 = 0.f, s2 = 0.f;
        #pragma unroll
        for (int k = 0; k < 16; k++) {
            float v = whlds[r * 130 + og * 16 + k];
            s1 += v * av[og * 16 + k];
            s2 += v * av[128 + og * 16 + k];
        }
        plds[(r * 8 + og) * 2 + 0] = s1;
        plds[(r * 8 + og) * 2 + 1] = s2;
    }
    __syncthreads();
    if (t < 64) {
        int r = t & 31, which = t >> 5;
        float s = 0.f;
        #pragma unroll
        for (int og = 0; og < 8; og++) s += plds[(r * 8 + og) * 2 + which];
        if (which == 0) f1g[b * 2048 + n0 + r] = s;
        else            f2g[b * 2048 + n0 + r] = s;
    }
}

// ---------------- Kernel B: per (b,i) row max m and 1/l of softmax ----------
__global__ __launch_bounds__(256) void kB(const float* __restrict__ adj,
                                          const float* __restrict__ f1g,
                                          const float* __restrict__ f2g,
                                          float* __restrict__ mg,
                                          float* __restrict__ linvg) {
    int blk = blockIdx.x;
    int b = blk >> 11;
    int i = blk & 2047;
    int t = threadIdx.x;
    float f1v = f1g[b * 2048 + i];
    const float* arow  = adj + (size_t)i * 2048;
    const float* f2row = f2g + b * 2048;

    int j0 = t * 8;
    float4 a0 = *reinterpret_cast<const float4*>(arow + j0);
    float4 a1 = *reinterpret_cast<const float4*>(arow + j0 + 4);
    float4 q0 = *reinterpret_cast<const float4*>(f2row + j0);
    float4 q1 = *reinterpret_cast<const float4*>(f2row + j0 + 4);
    float avv[8] = {a0.x, a0.y, a0.z, a0.w, a1.x, a1.y, a1.z, a1.w};
    float qvv[8] = {q0.x, q0.y, q0.z, q0.w, q1.x, q1.y, q1.z, q1.w};

    float em[8];
    float mymax = NEG_INF;
    #pragma unroll
    for (int k = 0; k < 8; k++) {
        float x = f1v + qvv[k];
        x = fmaxf(x, ALPHA * x);                 // leaky_relu (monotonic)
        em[k] = avv[k] > 0.f ? x : NEG_INF;
        mymax = fmaxf(mymax, em[k]);
    }
    #pragma unroll
    for (int off = 32; off > 0; off >>= 1)
        mymax = fmaxf(mymax, __shfl_xor(mymax, off));

    __shared__ float redm[4];
    __shared__ float reds[4];
    int wv = t >> 6, lane = t & 63;
    if (lane == 0) redm[wv] = mymax;
    __syncthreads();
    float m = fmaxf(fmaxf(redm[0], redm[1]), fmaxf(redm[2], redm[3]));

    float s = 0.f;
    #pragma unroll
    for (int k = 0; k < 8; k++) s += __expf(em[k] - m);
    #pragma unroll
    for (int off = 32; off > 0; off >>= 1) s += __shfl_xor(s, off);
    if (lane == 0) reds[wv] = s;
    __syncthreads();
    if (t == 0) {
        float l = reds[0] + reds[1] + reds[2] + reds[3];
        mg[b * 2048 + i]    = m;
        linvg[b * 2048 + i] = 1.f / l;
    }
}

// ---------------- Kernel C: out = elu((1/l) P Wh + bias), P built in A-frag layout ----------
__global__ __launch_bounds__(256) void kC(const float* __restrict__ adj,
                                          const short* __restrict__ whT,
                                          const float* __restrict__ f1g,
                                          const float* __restrict__ f2g,
                                          const float* __restrict__ mg,
                                          const float* __restrict__ linvg,
                                          const float* __restrict__ bias,
                                          float* __restrict__ out) {
    int blk = blockIdx.x;
    int b      = blk >> 6;
    int i_tile = (blk & 63) * 32;
    int t = threadIdx.x;
    int w = t >> 6, lane = t & 63;
    int i_half = w & 1, o_half = w >> 1;
    int i_base = i_tile + i_half * 16;
    int o_base = o_half * 64;
    int il = lane & 15, quad = lane >> 4;

    int iA = i_base + il;
    float f1v = f1g[b * 2048 + iA];
    float mv  = mg[b * 2048 + iA];
    const float* arow  = adj + (size_t)iA * 2048;
    const float* f2row = f2g + b * 2048;

    const short* wb0 = whT + ((size_t)(b * 128 + o_base + 0 * 16 + il)) * 2048;
    const short* wb1 = whT + ((size_t)(b * 128 + o_base + 1 * 16 + il)) * 2048;
    const short* wb2 = whT + ((size_t)(b * 128 + o_base + 2 * 16 + il)) * 2048;
    const short* wb3 = whT + ((size_t)(b * 128 + o_base + 3 * 16 + il)) * 2048;

    f32x4 acc0 = {0.f, 0.f, 0.f, 0.f};
    f32x4 acc1 = {0.f, 0.f, 0.f, 0.f};
    f32x4 acc2 = {0.f, 0.f, 0.f, 0.f};
    f32x4 acc3 = {0.f, 0.f, 0.f, 0.f};

    for (int j0 = 0; j0 < 2048; j0 += 32) {
        int jb = j0 + quad * 8;
        float4 A0 = *reinterpret_cast<const float4*>(arow + jb);
        float4 A1 = *reinterpret_cast<const float4*>(arow + jb + 4);
        float4 Q0 = *reinterpret_cast<const float4*>(f2row + jb);
        float4 Q1 = *reinterpret_cast<const float4*>(f2row + jb + 4);
        float avv[8] = {A0.x, A0.y, A0.z, A0.w, A1.x, A1.y, A1.z, A1.w};
        float qvv[8] = {Q0.x, Q0.y, Q0.z, Q0.w, Q1.x, Q1.y, Q1.z, Q1.w};

        short8 af;
        #pragma unroll
        for (int k = 0; k < 8; k++) {
            float x = f1v + qvv[k];
            x = fmaxf(x, ALPHA * x);             // leaky_relu
            float e = avv[k] > 0.f ? x : NEG_INF;
            af[k] = f2bf(__expf(e - mv));        // unnormalized softmax numerator
        }

        short8 bf0 = *reinterpret_cast<const short8*>(wb0 + jb);
        short8 bf1 = *reinterpret_cast<const short8*>(wb1 + jb);
        short8 bf2 = *reinterpret_cast<const short8*>(wb2 + jb);
        short8 bf3 = *reinterpret_cast<const short8*>(wb3 + jb);

        acc0 = __builtin_amdgcn_mfma_f32_16x16x32_bf16(af, bf0, acc0, 0, 0, 0);
        acc1 = __builtin_amdgcn_mfma_f32_16x16x32_bf16(af, bf1, acc1, 0, 0, 0);
        acc2 = __builtin_amdgcn_mfma_f32_16x16x32_bf16(af, bf2, acc2, 0, 0, 0);
        acc3 = __builtin_amdgcn_mfma_f32_16x16x32_bf16(af, bf3, acc3, 0, 0, 0);
    }

    float linv4[4];
    #pragma unroll
    for (int r = 0; r < 4; r++) linv4[r] = linvg[b * 2048 + i_base + quad * 4 + r];

    f32x4 accs[4] = {acc0, acc1, acc2, acc3};
    #pragma unroll
    for (int t4 = 0; t4 < 4; t4++) {
        int oo = o_base + t4 * 16 + il;
        float bv = bias[oo];
        #pragma unroll
        for (int r = 0; r < 4; r++) {
            int i = i_base + quad * 4 + r;
            float v = accs[t4][r] * linv4[r] + bv;
            out[((size_t)(b * 2048 + i)) * 128 + oo] = v > 0.f ? v : (__expf(v) - 1.f);
        }
    }
}

extern "C" void kernel_launch(void* const* d_in, const int* in_sizes, int n_in,
                              void* d_out, int out_size, void* d_ws, size_t ws_size,
                              hipStream_t stream) {
    const float* h    = (const float*)d_in[0];
    const float* adj  = (const float*)d_in[1];
    const float* W    = (const float*)d_in[2];
    const float* av   = (const float*)d_in[3];
    const float* bias = (const float*)d_in[4];
    float* out = (float*)d_out;

    char* ws = (char*)d_ws;
    short* whT  = (short*)ws;                    // 8*128*2048 bf16 = 4 MB
    float* f1g  = (float*)(ws + (4 << 20));      // 16384 fp32
    float* f2g  = f1g + 16384;
    float* mg   = f2g + 16384;
    float* linvg = mg + 16384;

    kA<<<512, 256, 0, stream>>>(h, W, av, whT, f1g, f2g);
    kB<<<16384, 256, 0, stream>>>(adj, f1g, f2g, mg, linvg);
    kC<<<512, 256, 0, stream>>>(adj, whT, f1g, f2g, mg, linvg, bias, out);
}

// Round 2
// 189.311 us; speedup vs baseline: 1.0363x; 1.0363x over previous
//
#include <hip/hip_runtime.h>
#include <hip/hip_bf16.h>
#include <stdint.h>

#define ALPHA 0.2f
#define NEG_INF -9000000000000000.0f

typedef __attribute__((ext_vector_type(8))) short short8;
typedef __attribute__((ext_vector_type(4))) float f32x4;

__device__ inline short f2bf(float x) {
    union { __hip_bfloat16 b; short s; } u;
    u.b = __float2bfloat16(x);
    return u.s;
}

// ---------------- Kernel A: Wh = h@W (fp32), store WhT bf16 [b][o][n]; f1,f2 fp32 ----------
__global__ __launch_bounds__(256) void kA(const float* __restrict__ h,
                                          const float* __restrict__ W,
                                          const float* __restrict__ av,
                                          short* __restrict__ whT,
                                          float* __restrict__ f1g,
                                          float* __restrict__ f2g) {
    int blk = blockIdx.x;
    int b  = blk >> 6;            // 8 batches
    int n0 = (blk & 63) * 32;     // 64 row-tiles of 32
    __shared__ float hlds[32 * 128];
    __shared__ float whlds[32 * 130];
    __shared__ float plds[32 * 8 * 2];
    int t = threadIdx.x;

    const float4* hsrc = reinterpret_cast<const float4*>(h + ((size_t)(b * 2048 + n0)) * 128);
    float4* hl4 = reinterpret_cast<float4*>(hlds);
    #pragma unroll
    for (int k = 0; k < 4; k++) hl4[t + k * 256] = hsrc[t + k * 256];
    __syncthreads();

    int o  = t & 127;
    int rg = t >> 7;  // 0..1 -> rows rg*16..rg*16+15
    float acc[16];
    #pragma unroll
    for (int r = 0; r < 16; r++) acc[r] = 0.f;
    for (int f = 0; f < 128; f++) {
        float wv = W[f * 128 + o];
        #pragma unroll
        for (int r = 0; r < 16; r++)
            acc[r] += hlds[(rg * 16 + r) * 128 + f] * wv;
    }

    {
        short8 lo, hi;
        #pragma unroll
        for (int r = 0; r < 8; r++)  lo[r] = f2bf(acc[r]);
        #pragma unroll
        for (int r = 0; r < 8; r++)  hi[r] = f2bf(acc[r + 8]);
        size_t base = ((size_t)(b * 128 + o)) * 2048 + n0 + rg * 16;
        *reinterpret_cast<short8*>(whT + base)     = lo;
        *reinterpret_cast<short8*>(whT + base + 8) = hi;
    }

    #pragma unroll
    for (int r = 0; r < 16; r++) whlds[(rg * 16 + r) * 130 + o] = acc[r];
    __syncthreads();

    {
        int r = t & 31, og = t >> 5;
        float s1 = 0.f, s2 = 0.f;
        #pragma unroll
        for (int k = 0; k < 16; k++) {
            float v = whlds[r * 130 + og * 16 + k];
            s1 += v * av[og * 16 + k];
            s2 += v * av[128 + og * 16 + k];
        }
        plds[(r * 8 + og) * 2 + 0] = s1;
        plds[(r * 8 + og) * 2 + 1] = s2;
    }
    __syncthreads();
    if (t < 64) {
        int r = t & 31, which = t >> 5;
        float s = 0.f;
        #pragma unroll
        for (int og = 0; og < 8; og++) s += plds[(r * 8 + og) * 2 + which];
        if (which == 0) f1g[b * 2048 + n0 + r] = s;
        else            f2g[b * 2048 + n0 + r] = s;
    }
}

// ---------------- Kernel P: per (b,i): m, l, write normalized P bf16 row ----------
__global__ __launch_bounds__(256) void kP(const float* __restrict__ adj,
                                          const float* __restrict__ f1g,
                                          const float* __restrict__ f2g,
                                          short* __restrict__ P) {
    int blk = blockIdx.x;
    int b = blk >> 11;
    int i = blk & 2047;
    int t = threadIdx.x;
    float f1v = f1g[b * 2048 + i];
    const float* arow  = adj + (size_t)i * 2048;
    const float* f2row = f2g + b * 2048;

    int j0 = t * 8;
    float4 a0 = *reinterpret_cast<const float4*>(arow + j0);
    float4 a1 = *reinterpret_cast<const float4*>(arow + j0 + 4);
    float4 q0 = *reinterpret_cast<const float4*>(f2row + j0);
    float4 q1 = *reinterpret_cast<const float4*>(f2row + j0 + 4);
    float avv[8] = {a0.x, a0.y, a0.z, a0.w, a1.x, a1.y, a1.z, a1.w};
    float qvv[8] = {q0.x, q0.y, q0.z, q0.w, q1.x, q1.y, q1.z, q1.w};

    float em[8];
    float mymax = NEG_INF;
    #pragma unroll
    for (int k = 0; k < 8; k++) {
        float x = f1v + qvv[k];
        x = fmaxf(x, ALPHA * x);                 // leaky_relu (monotonic)
        em[k] = avv[k] > 0.f ? x : NEG_INF;
        mymax = fmaxf(mymax, em[k]);
    }
    #pragma unroll
    for (int off = 32; off > 0; off >>= 1)
        mymax = fmaxf(mymax, __shfl_xor(mymax, off));

    __shared__ float redm[4];
    __shared__ float reds[4];
    int wv = t >> 6, lane = t & 63;
    if (lane == 0) redm[wv] = mymax;
    __syncthreads();
    float m = fmaxf(fmaxf(redm[0], redm[1]), fmaxf(redm[2], redm[3]));

    float ev[8];
    float s = 0.f;
    #pragma unroll
    for (int k = 0; k < 8; k++) { ev[k] = __expf(em[k] - m); s += ev[k]; }
    #pragma unroll
    for (int off = 32; off > 0; off >>= 1) s += __shfl_xor(s, off);
    if (lane == 0) reds[wv] = s;
    __syncthreads();
    float linv = 1.f / (reds[0] + reds[1] + reds[2] + reds[3]);

    short8 pv;
    #pragma unroll
    for (int k = 0; k < 8; k++) pv[k] = f2bf(ev[k] * linv);
    *reinterpret_cast<short8*>(P + ((size_t)(b * 2048 + i)) * 2048 + j0) = pv;
}

// ---------------- Kernel G: out = elu(P @ WhT^T + bias) — pure bf16 MFMA GEMM ----------
// block = 256 thr = 4 waves; tile 32i x 64o; wave: 16i x 32o (2 B-frags, 2 MFMA/iter)
__global__ __launch_bounds__(256) void kG(const short* __restrict__ P,
                                          const short* __restrict__ whT,
                                          const float* __restrict__ bias,
                                          float* __restrict__ out) {
    int blk = blockIdx.x;
    int b    = blk >> 7;
    int rem  = blk & 127;
    int i_tile = (rem >> 1) * 32;
    int o_tile = (rem & 1) * 64;
    int t = threadIdx.x;
    int w = t >> 6, lane = t & 63;
    int i_base = i_tile + (w & 1) * 16;
    int o_sub  = o_tile + (w >> 1) * 32;
    int il = lane & 15, quad = lane >> 4;

    const short* prow = P   + ((size_t)(b * 2048 + i_base + il)) * 2048;
    const short* wb0  = whT + ((size_t)(b * 128 + o_sub + il)) * 2048;
    const short* wb1  = whT + ((size_t)(b * 128 + o_sub + 16 + il)) * 2048;

    f32x4 acc0 = {0.f, 0.f, 0.f, 0.f};
    f32x4 acc1 = {0.f, 0.f, 0.f, 0.f};

    int jb = quad * 8;
    short8 aC  = *reinterpret_cast<const short8*>(prow + jb);
    short8 b0C = *reinterpret_cast<const short8*>(wb0 + jb);
    short8 b1C = *reinterpret_cast<const short8*>(wb1 + jb);

    #pragma unroll 4
    for (int j0 = 32; j0 < 2048; j0 += 32) {
        int o = j0 + jb;
        short8 aN  = *reinterpret_cast<const short8*>(prow + o);
        short8 b0N = *reinterpret_cast<const short8*>(wb0 + o);
        short8 b1N = *reinterpret_cast<const short8*>(wb1 + o);
        acc0 = __builtin_amdgcn_mfma_f32_16x16x32_bf16(aC, b0C, acc0, 0, 0, 0);
        acc1 = __builtin_amdgcn_mfma_f32_16x16x32_bf16(aC, b1C, acc1, 0, 0, 0);
        aC = aN; b0C = b0N; b1C = b1N;
    }
    acc0 = __builtin_amdgcn_mfma_f32_16x16x32_bf16(aC, b0C, acc0, 0, 0, 0);
    acc1 = __builtin_amdgcn_mfma_f32_16x16x32_bf16(aC, b1C, acc1, 0, 0, 0);

    f32x4 accs[2] = {acc0, acc1};
    #pragma unroll
    for (int t2 = 0; t2 < 2; t2++) {
        int oo = o_sub + t2 * 16 + il;
        float bv = bias[oo];
        #pragma unroll
        for (int r = 0; r < 4; r++) {
            int i = i_base + quad * 4 + r;
            float v = accs[t2][r] + bv;
            out[((size_t)(b * 2048 + i)) * 128 + oo] = v > 0.f ? v : (__expf(v) - 1.f);
        }
    }
}

// ---------------- Fallback (round-1) kernels: used only if ws too small ----------
__global__ __launch_bounds__(256) void kB(const float* __restrict__ adj,
                                          const float* __restrict__ f1g,
                                          const float* __restrict__ f2g,
                                          float* __restrict__ mg,
                                          float* __restrict__ linvg) {
    int blk = blockIdx.x;
    int b = blk >> 11;
    int i = blk & 2047;
    int t = threadIdx.x;
    float f1v = f1g[b * 2048 + i];
    const float* arow  = adj + (size_t)i * 2048;
    const float* f2row = f2g + b * 2048;

    int j0 = t * 8;
    float4 a0 = *reinterpret_cast<const float4*>(arow + j0);
    float4 a1 = *reinterpret_cast<const float4*>(arow + j0 + 4);
    float4 q0 = *reinterpret_cast<const float4*>(f2row + j0);
    float4 q1 = *reinterpret_cast<const float4*>(f2row + j0 + 4);
    float avv[8] = {a0.x, a0.y, a0.z, a0.w, a1.x, a1.y, a1.z, a1.w};
    float qvv[8] = {q0.x, q0.y, q0.z, q0.w, q1.x, q1.y, q1.z, q1.w};

    float em[8];
    float mymax = NEG_INF;
    #pragma unroll
    for (int k = 0; k < 8; k++) {
        float x = f1v + qvv[k];
        x = fmaxf(x, ALPHA * x);
        em[k] = avv[k] > 0.f ? x : NEG_INF;
        mymax = fmaxf(mymax, em[k]);
    }
    #pragma unroll
    for (int off = 32; off > 0; off >>= 1)
        mymax = fmaxf(mymax, __shfl_xor(mymax, off));

    __shared__ float redm[4];
    __shared__ float reds[4];
    int wv = t >> 6, lane = t & 63;
    if (lane == 0) redm[wv] = mymax;
    __syncthreads();
    float m = fmaxf(fmaxf(redm[0], redm[1]), fmaxf(redm[2], redm[3]));

    float s = 0.f;
    #pragma unroll
    for (int k = 0; k < 8; k++) s += __expf(em[k] - m);
    #pragma unroll
    for (int off = 32; off > 0; off >>= 1) s += __shfl_xor(s, off);
    if (lane == 0) reds[wv] = s;
    __syncthreads();
    if (t == 0) {
        float l = reds[0] + reds[1] + reds[2] + reds[3];
        mg[b * 2048 + i]    = m;
        linvg[b * 2048 + i] = 1.f / l;
    }
}

__global__ __launch_bounds__(256) void kC(const float* __restrict__ adj,
                                          const short* __restrict__ whT,
                                          const float* __restrict__ f1g,
                                          const float* __restrict__ f2g,
                                          const float* __restrict__ mg,
                                          const float* __restrict__ linvg,
                                          const float* __restrict__ bias,
                                          float* __restrict__ out) {
    int blk = blockIdx.x;
    int b      = blk >> 6;
    int i_tile = (blk & 63) * 32;
    int t = threadIdx.x;
    int w = t >> 6, lane = t & 63;
    int i_half = w & 1, o_half = w >> 1;
    int i_base = i_tile + i_half * 16;
    int o_base = o_half * 64;
    int il = lane & 15, quad = lane >> 4;

    int iA = i_base + il;
    float f1v = f1g[b * 2048 + iA];
    float mv  = mg[b * 2048 + iA];
    const float* arow  = adj + (size_t)iA * 2048;
    const float* f2row = f2g + b * 2048;

    const short* wb0 = whT + ((size_t)(b * 128 + o_base + 0 * 16 + il)) * 2048;
    const short* wb1 = whT + ((size_t)(b * 128 + o_base + 1 * 16 + il)) * 2048;
    const short* wb2 = whT + ((size_t)(b * 128 + o_base + 2 * 16 + il)) * 2048;
    const short* wb3 = whT + ((size_t)(b * 128 + o_base + 3 * 16 + il)) * 2048;

    f32x4 acc0 = {0.f, 0.f, 0.f, 0.f};
    f32x4 acc1 = {0.f, 0.f, 0.f, 0.f};
    f32x4 acc2 = {0.f, 0.f, 0.f, 0.f};
    f32x4 acc3 = {0.f, 0.f, 0.f, 0.f};

    for (int j0 = 0; j0 < 2048; j0 += 32) {
        int jb = j0 + quad * 8;
        float4 A0 = *reinterpret_cast<const float4*>(arow + jb);
        float4 A1 = *reinterpret_cast<const float4*>(arow + jb + 4);
        float4 Q0 = *reinterpret_cast<const float4*>(f2row + jb);
        float4 Q1 = *reinterpret_cast<const float4*>(f2row + jb + 4);
        float avv[8] = {A0.x, A0.y, A0.z, A0.w, A1.x, A1.y, A1.z, A1.w};
        float qvv[8] = {Q0.x, Q0.y, Q0.z, Q0.w, Q1.x, Q1.y, Q1.z, Q1.w};

        short8 af;
        #pragma unroll
        for (int k = 0; k < 8; k++) {
            float x = f1v + qvv[k];
            x = fmaxf(x, ALPHA * x);
            float e = avv[k] > 0.f ? x : NEG_INF;
            af[k] = f2bf(__expf(e - mv));
        }

        short8 bf0 = *reinterpret_cast<const short8*>(wb0 + jb);
        short8 bf1 = *reinterpret_cast<const short8*>(wb1 + jb);
        short8 bf2 = *reinterpret_cast<const short8*>(wb2 + jb);
        short8 bf3 = *reinterpret_cast<const short8*>(wb3 + jb);

        acc0 = __builtin_amdgcn_mfma_f32_16x16x32_bf16(af, bf0, acc0, 0, 0, 0);
        acc1 = __builtin_amdgcn_mfma_f32_16x16x32_bf16(af, bf1, acc1, 0, 0, 0);
        acc2 = __builtin_amdgcn_mfma_f32_16x16x32_bf16(af, bf2, acc2, 0, 0, 0);
        acc3 = __builtin_amdgcn_mfma_f32_16x16x32_bf16(af, bf3, acc3, 0, 0, 0);
    }

    float linv4[4];
    #pragma unroll
    for (int r = 0; r < 4; r++) linv4[r] = linvg[b * 2048 + i_base + quad * 4 + r];

    f32x4 accs[4] = {acc0, acc1, acc2, acc3};
    #pragma unroll
    for (int t4 = 0; t4 < 4; t4++) {
        int oo = o_base + t4 * 16 + il;
        float bv = bias[oo];
        #pragma unroll
        for (int r = 0; r < 4; r++) {
            int i = i_base + quad * 4 + r;
            float v = accs[t4][r] * linv4[r] + bv;
            out[((size_t)(b * 2048 + i)) * 128 + oo] = v > 0.f ? v : (__expf(v) - 1.f);
        }
    }
}

extern "C" void kernel_launch(void* const* d_in, const int* in_sizes, int n_in,
                              void* d_out, int out_size, void* d_ws, size_t ws_size,
                              hipStream_t stream) {
    const float* h    = (const float*)d_in[0];
    const float* adj  = (const float*)d_in[1];
    const float* W    = (const float*)d_in[2];
    const float* av   = (const float*)d_in[3];
    const float* bias = (const float*)d_in[4];
    float* out = (float*)d_out;

    char* ws = (char*)d_ws;
    short* whT  = (short*)ws;                    // 8*128*2048 bf16 = 4 MB
    float* f1g  = (float*)(ws + (4 << 20));      // 16384 fp32 = 64 KB
    float* f2g  = f1g + 16384;                   // 64 KB

    size_t P_off   = (4 << 20) + 2 * (16384 * sizeof(float));
    size_t P_bytes = (size_t)8 * 2048 * 2048 * 2;   // 64 MB
    bool big_ws = (ws_size >= P_off + P_bytes);

    kA<<<512, 256, 0, stream>>>(h, W, av, whT, f1g, f2g);

    if (big_ws) {
        short* P = (short*)(ws + P_off);
        kP<<<16384, 256, 0, stream>>>(adj, f1g, f2g, P);
        kG<<<1024, 256, 0, stream>>>(P, whT, bias, out);
    } else {
        float* mg    = f2g + 16384;
        float* linvg = mg + 16384;
        kB<<<16384, 256, 0, stream>>>(adj, f1g, f2g, mg, linvg);
        kC<<<512, 256, 0, stream>>>(adj, whT, f1g, f2g, mg, linvg, bias, out);
    }
}

// Round 3
// 136.432 us; speedup vs baseline: 1.4380x; 1.3876x over previous
//
#include <hip/hip_runtime.h>
#include <hip/hip_bf16.h>
#include <stdint.h>

#define ALPHA 0.2f
#define NEG_INF -9000000000000000.0f

typedef __attribute__((ext_vector_type(8))) short short8;
typedef __attribute__((ext_vector_type(4))) float f32x4;

__device__ inline short f2bf(float x) {
    union { __hip_bfloat16 b; short s; } u;
    u.b = __float2bfloat16(x);
    return u.s;
}

__device__ inline void gload16(const short* g, short* l) {
    __builtin_amdgcn_global_load_lds((const __attribute__((address_space(1))) unsigned int*)g,
                                     (__attribute__((address_space(3))) unsigned int*)l, 16, 0, 0);
}

// ---------------- Kernel A: Wh = h@W fp32 (4x4 register-blocked), WhT bf16, f1/f2 ----------
__global__ __launch_bounds__(256) void kA(const float* __restrict__ h,
                                          const float* __restrict__ W,
                                          const float* __restrict__ av,
                                          short* __restrict__ whT,
                                          float* __restrict__ f1g,
                                          float* __restrict__ f2g) {
    int blk = blockIdx.x;
    int b  = blk >> 6;            // 8 batches
    int n0 = (blk & 63) * 32;     // 64 row-tiles of 32
    __shared__ float hl[32 * 128];      // 16 KB
    __shared__ float wh[32 * 132];      // padded stride 132 (132*4B % 16 == 0)
    __shared__ float plds[32 * 8 * 2];
    int t = threadIdx.x;

    // stage h tile (32x128 fp32) coalesced
    const f32x4* hs = reinterpret_cast<const f32x4*>(h + ((size_t)(b * 2048 + n0)) * 128);
    f32x4* h4 = reinterpret_cast<f32x4*>(hl);
    #pragma unroll
    for (int k = 0; k < 4; k++) h4[t + k * 256] = hs[t + k * 256];
    __syncthreads();

    int og = t & 31, rg = t >> 5;   // thread computes rows r0..r0+3 x cols o0..o0+3
    int o0 = og * 4, r0 = rg * 4;
    f32x4 acc0 = {0.f,0.f,0.f,0.f}, acc1 = {0.f,0.f,0.f,0.f};
    f32x4 acc2 = {0.f,0.f,0.f,0.f}, acc3 = {0.f,0.f,0.f,0.f};
    const f32x4* W4  = reinterpret_cast<const f32x4*>(W);
    const f32x4* hv4 = reinterpret_cast<const f32x4*>(hl);
    for (int f0 = 0; f0 < 128; f0 += 4) {
        f32x4 h0 = hv4[(r0 + 0) * 32 + (f0 >> 2)];
        f32x4 h1 = hv4[(r0 + 1) * 32 + (f0 >> 2)];
        f32x4 h2 = hv4[(r0 + 2) * 32 + (f0 >> 2)];
        f32x4 h3 = hv4[(r0 + 3) * 32 + (f0 >> 2)];
        f32x4 w0 = W4[(f0 + 0) * 32 + og];
        f32x4 w1 = W4[(f0 + 1) * 32 + og];
        f32x4 w2 = W4[(f0 + 2) * 32 + og];
        f32x4 w3 = W4[(f0 + 3) * 32 + og];
        acc0 += h0[0] * w0 + h0[1] * w1 + h0[2] * w2 + h0[3] * w3;
        acc1 += h1[0] * w0 + h1[1] * w1 + h1[2] * w2 + h1[3] * w3;
        acc2 += h2[0] * w0 + h2[1] * w1 + h2[2] * w2 + h2[3] * w3;
        acc3 += h3[0] * w0 + h3[1] * w1 + h3[2] * w2 + h3[3] * w3;
    }
    *reinterpret_cast<f32x4*>(&wh[(r0 + 0) * 132 + o0]) = acc0;
    *reinterpret_cast<f32x4*>(&wh[(r0 + 1) * 132 + o0]) = acc1;
    *reinterpret_cast<f32x4*>(&wh[(r0 + 2) * 132 + o0]) = acc2;
    *reinterpret_cast<f32x4*>(&wh[(r0 + 3) * 132 + o0]) = acc3;
    __syncthreads();

    // WhT bf16 store: [b][o][n], 16B contiguous per thread
    {
        int o = t & 127, rg2 = t >> 7;
        short8 lo, hi;
        #pragma unroll
        for (int r = 0; r < 8; r++) lo[r] = f2bf(wh[(rg2 * 16 + r) * 132 + o]);
        #pragma unroll
        for (int r = 0; r < 8; r++) hi[r] = f2bf(wh[(rg2 * 16 + 8 + r) * 132 + o]);
        size_t base = ((size_t)(b * 128 + o)) * 2048 + n0 + rg2 * 16;
        *reinterpret_cast<short8*>(whT + base)     = lo;
        *reinterpret_cast<short8*>(whT + base + 8) = hi;
    }

    // f1/f2 reduction
    {
        int r = t & 31, og8 = t >> 5;
        float s1 = 0.f, s2 = 0.f;
        #pragma unroll
        for (int k = 0; k < 16; k++) {
            float v = wh[r * 132 + og8 * 16 + k];
            s1 += v * av[og8 * 16 + k];
            s2 += v * av[128 + og8 * 16 + k];
        }
        plds[(r * 8 + og8) * 2 + 0] = s1;
        plds[(r * 8 + og8) * 2 + 1] = s2;
    }
    __syncthreads();
    if (t < 64) {
        int r = t & 31, which = t >> 5;
        float s = 0.f;
        #pragma unroll
        for (int og8 = 0; og8 < 8; og8++) s += plds[(r * 8 + og8) * 2 + which];
        if (which == 0) f1g[b * 2048 + n0 + r] = s;
        else            f2g[b * 2048 + n0 + r] = s;
    }
}

// ---------------- Kernel P: one block per i, all 8 batches; writes normalized P bf16 ----------
__global__ __launch_bounds__(256) void kP(const float* __restrict__ adj,
                                          const float* __restrict__ f1g,
                                          const float* __restrict__ f2g,
                                          short* __restrict__ P) {
    int i = blockIdx.x;           // 2048
    int t = threadIdx.x;
    int wv = t >> 6, lane = t & 63;
    int j0 = t * 8;
    const float* arow = adj + (size_t)i * 2048;
    f32x4 a0 = *reinterpret_cast<const f32x4*>(arow + j0);
    f32x4 a1 = *reinterpret_cast<const f32x4*>(arow + j0 + 4);
    float avv[8];
    #pragma unroll
    for (int k = 0; k < 4; k++) { avv[k] = a0[k]; avv[k + 4] = a1[k]; }

    __shared__ float redm[4];
    __shared__ float reds[4];

    for (int b = 0; b < 8; b++) {
        float f1v = f1g[b * 2048 + i];
        const float* f2row = f2g + b * 2048 + j0;
        f32x4 q0 = *reinterpret_cast<const f32x4*>(f2row);
        f32x4 q1 = *reinterpret_cast<const f32x4*>(f2row + 4);
        float em[8];
        float mymax = NEG_INF;
        #pragma unroll
        for (int k = 0; k < 8; k++) {
            float q = (k < 4) ? q0[k] : q1[k - 4];
            float x = f1v + q;
            x = fmaxf(x, ALPHA * x);                 // leaky_relu (monotonic)
            em[k] = avv[k] > 0.f ? x : NEG_INF;
            mymax = fmaxf(mymax, em[k]);
        }
        #pragma unroll
        for (int off = 32; off > 0; off >>= 1)
            mymax = fmaxf(mymax, __shfl_xor(mymax, off));
        if (lane == 0) redm[wv] = mymax;
        __syncthreads();
        float m = fmaxf(fmaxf(redm[0], redm[1]), fmaxf(redm[2], redm[3]));

        float ev[8];
        float s = 0.f;
        #pragma unroll
        for (int k = 0; k < 8; k++) { ev[k] = __expf(em[k] - m); s += ev[k]; }
        #pragma unroll
        for (int off = 32; off > 0; off >>= 1) s += __shfl_xor(s, off);
        if (lane == 0) reds[wv] = s;
        __syncthreads();
        float linv = 1.f / (reds[0] + reds[1] + reds[2] + reds[3]);

        short8 pv;
        #pragma unroll
        for (int k = 0; k < 8; k++) pv[k] = f2bf(ev[k] * linv);
        *reinterpret_cast<short8*>(P + ((size_t)(b * 2048 + i)) * 2048 + j0) = pv;
    }
}

// ---------------- Kernel G: out = elu(P @ WhT^T + bias) — LDS-staged MFMA GEMM ----------
// 256 blocks: tile 64i x 128o, BK=32, 3-deep async ring, swizzled LDS.
__global__ __launch_bounds__(256) void kG(const short* __restrict__ P,
                                          const short* __restrict__ whT,
                                          const float* __restrict__ bias,
                                          float* __restrict__ out) {
    int blk = blockIdx.x;
    int b      = blk >> 5;
    int i_tile = (blk & 31) * 64;
    int t = threadIdx.x;
    int w = t >> 6, lane = t & 63, il = lane & 15, quad = lane >> 4;
    int iw = (w & 1) * 32, ow = (w >> 1) * 64;

    __shared__ short Al[3][64 * 32];    // 12 KB
    __shared__ short Bl[3][128 * 32];   // 24 KB

    // staging: thread t loads row r=t>>2, col-slot cs=t&3; global colblk = cs ^ ((r>>1)&3)
    int r  = t >> 2, cs = t & 3;
    int rB1 = r + 64;
    const short* gA  = P   + ((size_t)(b * 2048 + i_tile + r)) * 2048 + ((cs ^ ((r  >> 1) & 3)) << 3);
    const short* gB0 = whT + ((size_t)(b * 128 + r))           * 2048 + ((cs ^ ((r  >> 1) & 3)) << 3);
    const short* gB1 = whT + ((size_t)(b * 128 + rB1))         * 2048 + ((cs ^ ((rB1 >> 1) & 3)) << 3);
    int lslot = t * 8;   // shorts

    // frag read offsets (shorts): row*32 + ((quad ^ ((row>>1)&3))*8); (row>>1)&3 == (il>>1)&3 here
    int sw = (quad ^ ((il >> 1) & 3)) << 3;
    int offA0 = (iw + il) * 32 + sw;
    int offA1 = (iw + 16 + il) * 32 + sw;
    int offB0 = (ow + 0  + il) * 32 + sw;
    int offB1 = (ow + 16 + il) * 32 + sw;
    int offB2 = (ow + 32 + il) * 32 + sw;
    int offB3 = (ow + 48 + il) * 32 + sw;

    f32x4 acc[2][4];
    #pragma unroll
    for (int a = 0; a < 2; a++)
        #pragma unroll
        for (int t4 = 0; t4 < 4; t4++) acc[a][t4] = (f32x4){0.f, 0.f, 0.f, 0.f};

    // prologue: stage tiles 0 and 1
    gload16(gA,       &Al[0][lslot]);
    gload16(gB0,      &Bl[0][lslot]);
    gload16(gB1,      &Bl[0][2048 + lslot]);
    gload16(gA  + 32, &Al[1][lslot]);
    gload16(gB0 + 32, &Bl[1][lslot]);
    gload16(gB1 + 32, &Bl[1][2048 + lslot]);

    int bufc = 0;
    for (int kb = 0; kb < 64; kb++) {
        // B1: drain the oldest 3 loads (tile kb); keep tile kb+1 in flight
        __asm__ __volatile__("" ::: "memory");
        if (kb == 63) __builtin_amdgcn_s_waitcnt(0x0F70);   // vmcnt(0)
        else          __builtin_amdgcn_s_waitcnt(0x0F73);   // vmcnt(3)
        __builtin_amdgcn_s_barrier();
        __asm__ __volatile__("" ::: "memory");

        // stage tile kb+2 into the buffer last read at iter kb-1 (safe: after B2(kb-1) < B1(kb))
        if (kb < 62) {
            int bn = bufc + 2; if (bn >= 3) bn -= 3;
            int ko = (kb + 2) * 32;
            gload16(gA  + ko, &Al[bn][lslot]);
            gload16(gB0 + ko, &Bl[bn][lslot]);
            gload16(gB1 + ko, &Bl[bn][2048 + lslot]);
        }

        const short* Ab = &Al[bufc][0];
        const short* Bb = &Bl[bufc][0];
        short8 a0 = *reinterpret_cast<const short8*>(Ab + offA0);
        short8 a1 = *reinterpret_cast<const short8*>(Ab + offA1);
        short8 b0 = *reinterpret_cast<const short8*>(Bb + offB0);
        short8 b1 = *reinterpret_cast<const short8*>(Bb + offB1);
        short8 b2 = *reinterpret_cast<const short8*>(Bb + offB2);
        short8 b3 = *reinterpret_cast<const short8*>(Bb + offB3);

        // B2: frag reads landed (lgkmcnt 0, vmcnt untouched) -> buffer may be re-staged next iter
        __asm__ __volatile__("" ::: "memory");
        __builtin_amdgcn_s_waitcnt(0xC07F);                 // lgkmcnt(0) only
        __builtin_amdgcn_s_barrier();
        __asm__ __volatile__("" ::: "memory");

        acc[0][0] = __builtin_amdgcn_mfma_f32_16x16x32_bf16(a0, b0, acc[0][0], 0, 0, 0);
        acc[0][1] = __builtin_amdgcn_mfma_f32_16x16x32_bf16(a0, b1, acc[0][1], 0, 0, 0);
        acc[0][2] = __builtin_amdgcn_mfma_f32_16x16x32_bf16(a0, b2, acc[0][2], 0, 0, 0);
        acc[0][3] = __builtin_amdgcn_mfma_f32_16x16x32_bf16(a0, b3, acc[0][3], 0, 0, 0);
        acc[1][0] = __builtin_amdgcn_mfma_f32_16x16x32_bf16(a1, b0, acc[1][0], 0, 0, 0);
        acc[1][1] = __builtin_amdgcn_mfma_f32_16x16x32_bf16(a1, b1, acc[1][1], 0, 0, 0);
        acc[1][2] = __builtin_amdgcn_mfma_f32_16x16x32_bf16(a1, b2, acc[1][2], 0, 0, 0);
        acc[1][3] = __builtin_amdgcn_mfma_f32_16x16x32_bf16(a1, b3, acc[1][3], 0, 0, 0);

        bufc++; if (bufc >= 3) bufc = 0;
    }

    #pragma unroll
    for (int a = 0; a < 2; a++) {
        #pragma unroll
        for (int t4 = 0; t4 < 4; t4++) {
            int oo = ow + t4 * 16 + il;
            float bv = bias[oo];
            #pragma unroll
            for (int rr = 0; rr < 4; rr++) {
                int ii = i_tile + iw + a * 16 + quad * 4 + rr;
                float v = acc[a][t4][rr] + bv;
                out[((size_t)(b * 2048 + ii)) * 128 + oo] = v > 0.f ? v : (__expf(v) - 1.f);
            }
        }
    }
}

extern "C" void kernel_launch(void* const* d_in, const int* in_sizes, int n_in,
                              void* d_out, int out_size, void* d_ws, size_t ws_size,
                              hipStream_t stream) {
    const float* h    = (const float*)d_in[0];
    const float* adj  = (const float*)d_in[1];
    const float* W    = (const float*)d_in[2];
    const float* av   = (const float*)d_in[3];
    const float* bias = (const float*)d_in[4];
    float* out = (float*)d_out;

    char* ws = (char*)d_ws;
    short* whT = (short*)ws;                     // 8*128*2048 bf16 = 4 MB
    float* f1g = (float*)(ws + (4 << 20));       // 64 KB
    float* f2g = f1g + 16384;                    // 64 KB
    short* P   = (short*)(ws + (4 << 20) + 2 * 16384 * sizeof(float));  // 64 MB

    kA<<<512, 256, 0, stream>>>(h, W, av, whT, f1g, f2g);
    kP<<<2048, 256, 0, stream>>>(adj, f1g, f2g, P);
    kG<<<256, 256, 0, stream>>>(P, whT, bias, out);
}

// Round 4
// 126.168 us; speedup vs baseline: 1.5550x; 1.0813x over previous
//
#include <hip/hip_runtime.h>
#include <hip/hip_bf16.h>
#include <stdint.h>

#define ALPHA 0.2f

typedef __attribute__((ext_vector_type(8))) short short8;
typedef __attribute__((ext_vector_type(4))) float f32x4;

__device__ inline short f2bf(float x) {
    union { __hip_bfloat16 b; short s; } u;
    u.b = __float2bfloat16(x);
    return u.s;
}

__device__ inline void gload16(const short* g, short* l) {
    __builtin_amdgcn_global_load_lds((const __attribute__((address_space(1))) unsigned int*)g,
                                     (__attribute__((address_space(3))) unsigned int*)l, 16, 0, 0);
}

// ---------------- Kernel A: Wh = h@W fp32 (4x4 register-blocked), WhT bf16, f1/f2 ----------
__global__ __launch_bounds__(256) void kA(const float* __restrict__ h,
                                          const float* __restrict__ W,
                                          const float* __restrict__ av,
                                          short* __restrict__ whT,
                                          float* __restrict__ f1g,
                                          float* __restrict__ f2g) {
    int blk = blockIdx.x;
    int b  = blk >> 6;            // 8 batches
    int n0 = (blk & 63) * 32;     // 64 row-tiles of 32
    __shared__ float hl[32 * 128];
    __shared__ float wh[32 * 132];
    __shared__ float plds[32 * 8 * 2];
    int t = threadIdx.x;

    const f32x4* hs = reinterpret_cast<const f32x4*>(h + ((size_t)(b * 2048 + n0)) * 128);
    f32x4* h4 = reinterpret_cast<f32x4*>(hl);
    #pragma unroll
    for (int k = 0; k < 4; k++) h4[t + k * 256] = hs[t + k * 256];
    __syncthreads();

    int og = t & 31, rg = t >> 5;
    int o0 = og * 4, r0 = rg * 4;
    f32x4 acc0 = {0.f,0.f,0.f,0.f}, acc1 = {0.f,0.f,0.f,0.f};
    f32x4 acc2 = {0.f,0.f,0.f,0.f}, acc3 = {0.f,0.f,0.f,0.f};
    const f32x4* W4  = reinterpret_cast<const f32x4*>(W);
    const f32x4* hv4 = reinterpret_cast<const f32x4*>(hl);
    for (int f0 = 0; f0 < 128; f0 += 4) {
        f32x4 h0 = hv4[(r0 + 0) * 32 + (f0 >> 2)];
        f32x4 h1 = hv4[(r0 + 1) * 32 + (f0 >> 2)];
        f32x4 h2 = hv4[(r0 + 2) * 32 + (f0 >> 2)];
        f32x4 h3 = hv4[(r0 + 3) * 32 + (f0 >> 2)];
        f32x4 w0 = W4[(f0 + 0) * 32 + og];
        f32x4 w1 = W4[(f0 + 1) * 32 + og];
        f32x4 w2 = W4[(f0 + 2) * 32 + og];
        f32x4 w3 = W4[(f0 + 3) * 32 + og];
        acc0 += h0[0] * w0 + h0[1] * w1 + h0[2] * w2 + h0[3] * w3;
        acc1 += h1[0] * w0 + h1[1] * w1 + h1[2] * w2 + h1[3] * w3;
        acc2 += h2[0] * w0 + h2[1] * w1 + h2[2] * w2 + h2[3] * w3;
        acc3 += h3[0] * w0 + h3[1] * w1 + h3[2] * w2 + h3[3] * w3;
    }
    *reinterpret_cast<f32x4*>(&wh[(r0 + 0) * 132 + o0]) = acc0;
    *reinterpret_cast<f32x4*>(&wh[(r0 + 1) * 132 + o0]) = acc1;
    *reinterpret_cast<f32x4*>(&wh[(r0 + 2) * 132 + o0]) = acc2;
    *reinterpret_cast<f32x4*>(&wh[(r0 + 3) * 132 + o0]) = acc3;
    __syncthreads();

    {
        int o = t & 127, rg2 = t >> 7;
        short8 lo, hi;
        #pragma unroll
        for (int r = 0; r < 8; r++) lo[r] = f2bf(wh[(rg2 * 16 + r) * 132 + o]);
        #pragma unroll
        for (int r = 0; r < 8; r++) hi[r] = f2bf(wh[(rg2 * 16 + 8 + r) * 132 + o]);
        size_t base = ((size_t)(b * 128 + o)) * 2048 + n0 + rg2 * 16;
        *reinterpret_cast<short8*>(whT + base)     = lo;
        *reinterpret_cast<short8*>(whT + base + 8) = hi;
    }

    {
        int r = t & 31, og8 = t >> 5;
        float s1 = 0.f, s2 = 0.f;
        #pragma unroll
        for (int k = 0; k < 16; k++) {
            float v = wh[r * 132 + og8 * 16 + k];
            s1 += v * av[og8 * 16 + k];
            s2 += v * av[128 + og8 * 16 + k];
        }
        plds[(r * 8 + og8) * 2 + 0] = s1;
        plds[(r * 8 + og8) * 2 + 1] = s2;
    }
    __syncthreads();
    if (t < 64) {
        int r = t & 31, which = t >> 5;
        float s = 0.f;
        #pragma unroll
        for (int og8 = 0; og8 < 8; og8++) s += plds[(r * 8 + og8) * 2 + which];
        if (which == 0) f1g[b * 2048 + n0 + r] = s;
        else            f2g[b * 2048 + n0 + r] = s;
    }
}

// ---------------- Kernel M: pack adj (2048x2048 fp32) -> bitmask [i][64 words] ----------
__global__ __launch_bounds__(256) void kM(const float* __restrict__ adj,
                                          uint32_t* __restrict__ maskg) {
    int gt = blockIdx.x * 256 + threadIdx.x;   // 131072 threads
    int i = gt >> 6, wd = gt & 63;
    const float* src = adj + (size_t)i * 2048 + wd * 32;
    uint32_t m = 0;
    #pragma unroll
    for (int k = 0; k < 32; k += 4) {
        f32x4 v = *reinterpret_cast<const f32x4*>(src + k);
        if (v[0] > 0.f) m |= 1u << (k + 0);
        if (v[1] > 0.f) m |= 1u << (k + 1);
        if (v[2] > 0.f) m |= 1u << (k + 2);
        if (v[3] > 0.f) m |= 1u << (k + 3);
    }
    maskg[i * 64 + wd] = m;
}

// ---------------- Kernel G2: fused E=exp(lrelu(f1+f2))*mask, O=E@Wh^T, out=elu(O/l+bias) ----
// grid 512: (b, 32i-tile); full o=128. BK=32, 3-deep B-ring, no score-matrix traffic.
__global__ __launch_bounds__(256) void kG2(const uint32_t* __restrict__ maskg,
                                           const short* __restrict__ whT,
                                           const float* __restrict__ f1g,
                                           const float* __restrict__ f2g,
                                           const float* __restrict__ bias,
                                           float* __restrict__ out) {
    int blk = blockIdx.x;
    int b      = blk >> 6;
    int i_tile = (blk & 63) * 32;
    int t = threadIdx.x;
    int w = t >> 6, lane = t & 63, il = lane & 15, quad = lane >> 4;
    int ihalf = w & 1, ohalf = w >> 1;
    int i_base = i_tile + ihalf * 16;
    int ow = ohalf * 64;

    __shared__ uint32_t m32l[32 * 68];   // stride 68: b128-aligned, 2-way-conflict (free)
    __shared__ float    f2l[2048];
    __shared__ short    Bl[3][128 * 32];
    __shared__ float    lred[32 * 4];
    __shared__ float    linvl[32];

    // B staging (round-3-verified swizzle)
    int r = t >> 2, cs = t & 3;
    int rB1 = r + 64;
    const short* gB0 = whT + ((size_t)(b * 128 + r))   * 2048 + ((cs ^ ((r   >> 1) & 3)) << 3);
    const short* gB1 = whT + ((size_t)(b * 128 + rB1)) * 2048 + ((cs ^ ((rB1 >> 1) & 3)) << 3);
    int lslot = t * 8;

    // prologue: stage B tiles 0,1
    gload16(gB0,      &Bl[0][lslot]);
    gload16(gB1,      &Bl[0][2048 + lslot]);
    gload16(gB0 + 32, &Bl[1][lslot]);
    gload16(gB1 + 32, &Bl[1][2048 + lslot]);

    // mask: 32 rows x 64 words, padded stride 68
    {
        const uint4* msrc = reinterpret_cast<const uint4*>(maskg + (size_t)i_tile * 64);
        #pragma unroll
        for (int rep = 0; rep < 2; rep++) {
            int idx = t + rep * 256;           // [0,512)
            uint4 v = msrc[idx];
            int row = idx >> 4, wq = (idx & 15) * 4;
            *reinterpret_cast<uint4*>(&m32l[row * 68 + wq]) = v;
        }
    }
    // f2 row
    {
        const f32x4* fsrc = reinterpret_cast<const f32x4*>(f2g + b * 2048);
        f32x4* fdst = reinterpret_cast<f32x4*>(f2l);
        fdst[t]       = fsrc[t];
        fdst[t + 256] = fsrc[t + 256];
    }
    float f1v = f1g[b * 2048 + i_base + il];

    int sw = (quad ^ ((il >> 1) & 3)) << 3;
    int offB0 = (ow + 0  + il) * 32 + sw;
    int offB1 = (ow + 16 + il) * 32 + sw;
    int offB2 = (ow + 32 + il) * 32 + sw;
    int offB3 = (ow + 48 + il) * 32 + sw;
    int mrow = (ihalf * 16 + il) * 68;

    f32x4 acc0 = {0.f,0.f,0.f,0.f}, acc1 = {0.f,0.f,0.f,0.f};
    f32x4 acc2 = {0.f,0.f,0.f,0.f}, acc3 = {0.f,0.f,0.f,0.f};
    float lpart = 0.f;

    __syncthreads();   // drains prologue loads + LDS stores

    int bufc = 0;
    for (int kb = 0; kb < 64; kb++) {
        __asm__ __volatile__("" ::: "memory");
        if (kb == 63) __builtin_amdgcn_s_waitcnt(0x0F70);   // vmcnt(0)
        else          __builtin_amdgcn_s_waitcnt(0x0F72);   // vmcnt(2): tile kb landed
        __builtin_amdgcn_s_barrier();
        __asm__ __volatile__("" ::: "memory");

        if (kb < 62) {
            int bn = bufc + 2; if (bn >= 3) bn -= 3;
            int ko = (kb + 2) * 32;
            gload16(gB0 + ko, &Bl[bn][lslot]);
            gload16(gB1 + ko, &Bl[bn][2048 + lslot]);
        }

        uint32_t mw = m32l[mrow + kb];
        f32x4 q0 = *reinterpret_cast<const f32x4*>(&f2l[kb * 32 + quad * 8]);
        f32x4 q1 = *reinterpret_cast<const f32x4*>(&f2l[kb * 32 + quad * 8 + 4]);

        short8 af;
        #pragma unroll
        for (int k = 0; k < 8; k++) {
            float qv = (k < 4) ? q0[k] : q1[k - 4];
            float x = f1v + qv;
            x = fmaxf(x, ALPHA * x);                       // leaky_relu
            float e = ((mw >> (quad * 8 + k)) & 1u) ? __expf(x) : 0.f;
            af[k] = f2bf(e);
            if (ohalf == 0) lpart += e;                    // wave-uniform branch
        }

        const short* Bb = &Bl[bufc][0];
        short8 b0 = *reinterpret_cast<const short8*>(Bb + offB0);
        short8 b1 = *reinterpret_cast<const short8*>(Bb + offB1);
        short8 b2 = *reinterpret_cast<const short8*>(Bb + offB2);
        short8 b3 = *reinterpret_cast<const short8*>(Bb + offB3);

        __asm__ __volatile__("" ::: "memory");
        __builtin_amdgcn_s_waitcnt(0xC07F);                // lgkmcnt(0) only
        __builtin_amdgcn_s_barrier();
        __asm__ __volatile__("" ::: "memory");

        acc0 = __builtin_amdgcn_mfma_f32_16x16x32_bf16(af, b0, acc0, 0, 0, 0);
        acc1 = __builtin_amdgcn_mfma_f32_16x16x32_bf16(af, b1, acc1, 0, 0, 0);
        acc2 = __builtin_amdgcn_mfma_f32_16x16x32_bf16(af, b2, acc2, 0, 0, 0);
        acc3 = __builtin_amdgcn_mfma_f32_16x16x32_bf16(af, b3, acc3, 0, 0, 0);

        bufc++; if (bufc >= 3) bufc = 0;
    }

    if (ohalf == 0) lred[(ihalf * 16 + il) * 4 + quad] = lpart;
    __syncthreads();
    if (t < 32) {
        float l = lred[t * 4] + lred[t * 4 + 1] + lred[t * 4 + 2] + lred[t * 4 + 3];
        linvl[t] = 1.f / l;
    }
    __syncthreads();

    f32x4 accs[4] = {acc0, acc1, acc2, acc3};
    #pragma unroll
    for (int t4 = 0; t4 < 4; t4++) {
        int oo = ow + t4 * 16 + il;
        float bv = bias[oo];
        #pragma unroll
        for (int rr = 0; rr < 4; rr++) {
            int irel = ihalf * 16 + quad * 4 + rr;
            float v = accs[t4][rr] * linvl[irel] + bv;
            int ii = i_tile + irel;
            out[((size_t)(b * 2048 + ii)) * 128 + oo] = v > 0.f ? v : (__expf(v) - 1.f);
        }
    }
}

extern "C" void kernel_launch(void* const* d_in, const int* in_sizes, int n_in,
                              void* d_out, int out_size, void* d_ws, size_t ws_size,
                              hipStream_t stream) {
    const float* h    = (const float*)d_in[0];
    const float* adj  = (const float*)d_in[1];
    const float* W    = (const float*)d_in[2];
    const float* av   = (const float*)d_in[3];
    const float* bias = (const float*)d_in[4];
    float* out = (float*)d_out;

    char* ws = (char*)d_ws;
    short*    whT   = (short*)ws;                       // 4 MB
    float*    f1g   = (float*)(ws + (4 << 20));         // 64 KB
    float*    f2g   = f1g + 16384;                      // 64 KB
    uint32_t* maskg = (uint32_t*)(ws + (5 << 20));      // 512 KB

    kM<<<512, 256, 0, stream>>>(adj, maskg);
    kA<<<512, 256, 0, stream>>>(h, W, av, whT, f1g, f2g);
    kG2<<<512, 256, 0, stream>>>(maskg, whT, f1g, f2g, bias, out);
}

// Round 5
// 122.360 us; speedup vs baseline: 1.6034x; 1.0311x over previous
//
#include <hip/hip_runtime.h>
#include <hip/hip_bf16.h>
#include <stdint.h>

#define ALPHA 0.2f

typedef __attribute__((ext_vector_type(8))) short short8;
typedef __attribute__((ext_vector_type(4))) float f32x4;

__device__ inline short f2bf(float x) {
    union { __hip_bfloat16 b; short s; } u;
    u.b = __float2bfloat16(x);
    return u.s;
}

__device__ inline void gload16(const short* g, short* l) {
    __builtin_amdgcn_global_load_lds((const __attribute__((address_space(1))) unsigned int*)g,
                                     (__attribute__((address_space(3))) unsigned int*)l, 16, 0, 0);
}

// ---------------- Kernel A: Wh = h@W fp32 (4x4 reg-blocked) + WhT bf16 + f1/f2 + mask-pack ---
__global__ __launch_bounds__(256) void kA(const float* __restrict__ h,
                                          const float* __restrict__ W,
                                          const float* __restrict__ av,
                                          const float* __restrict__ adj,
                                          short* __restrict__ whT,
                                          float* __restrict__ f1g,
                                          float* __restrict__ f2g,
                                          uint32_t* __restrict__ maskg) {
    int blk = blockIdx.x;
    int b  = blk >> 6;            // 8 batches
    int n0 = (blk & 63) * 32;     // 64 row-tiles of 32
    __shared__ float hl[32 * 128];
    __shared__ float wh[32 * 132];
    __shared__ float plds[32 * 8 * 2];
    int t = threadIdx.x;

    // folded kM: pack 1 mask word per thread (512 blk * 256 thr == 2048 rows * 64 words)
    {
        int gt = blk * 256 + t;
        int mi = gt >> 6, wd = gt & 63;
        const float* src = adj + (size_t)mi * 2048 + wd * 32;
        uint32_t m = 0;
        #pragma unroll
        for (int k = 0; k < 32; k += 4) {
            f32x4 v = *reinterpret_cast<const f32x4*>(src + k);
            if (v[0] > 0.f) m |= 1u << (k + 0);
            if (v[1] > 0.f) m |= 1u << (k + 1);
            if (v[2] > 0.f) m |= 1u << (k + 2);
            if (v[3] > 0.f) m |= 1u << (k + 3);
        }
        maskg[mi * 64 + wd] = m;
    }

    const f32x4* hs = reinterpret_cast<const f32x4*>(h + ((size_t)(b * 2048 + n0)) * 128);
    f32x4* h4 = reinterpret_cast<f32x4*>(hl);
    #pragma unroll
    for (int k = 0; k < 4; k++) h4[t + k * 256] = hs[t + k * 256];
    __syncthreads();

    int og = t & 31, rg = t >> 5;
    int o0 = og * 4, r0 = rg * 4;
    f32x4 acc0 = {0.f,0.f,0.f,0.f}, acc1 = {0.f,0.f,0.f,0.f};
    f32x4 acc2 = {0.f,0.f,0.f,0.f}, acc3 = {0.f,0.f,0.f,0.f};
    const f32x4* W4  = reinterpret_cast<const f32x4*>(W);
    const f32x4* hv4 = reinterpret_cast<const f32x4*>(hl);
    #pragma unroll 4
    for (int f0 = 0; f0 < 128; f0 += 4) {
        f32x4 h0 = hv4[(r0 + 0) * 32 + (f0 >> 2)];
        f32x4 h1 = hv4[(r0 + 1) * 32 + (f0 >> 2)];
        f32x4 h2 = hv4[(r0 + 2) * 32 + (f0 >> 2)];
        f32x4 h3 = hv4[(r0 + 3) * 32 + (f0 >> 2)];
        f32x4 w0 = W4[(f0 + 0) * 32 + og];
        f32x4 w1 = W4[(f0 + 1) * 32 + og];
        f32x4 w2 = W4[(f0 + 2) * 32 + og];
        f32x4 w3 = W4[(f0 + 3) * 32 + og];
        acc0 += h0[0] * w0 + h0[1] * w1 + h0[2] * w2 + h0[3] * w3;
        acc1 += h1[0] * w0 + h1[1] * w1 + h1[2] * w2 + h1[3] * w3;
        acc2 += h2[0] * w0 + h2[1] * w1 + h2[2] * w2 + h2[3] * w3;
        acc3 += h3[0] * w0 + h3[1] * w1 + h3[2] * w2 + h3[3] * w3;
    }
    *reinterpret_cast<f32x4*>(&wh[(r0 + 0) * 132 + o0]) = acc0;
    *reinterpret_cast<f32x4*>(&wh[(r0 + 1) * 132 + o0]) = acc1;
    *reinterpret_cast<f32x4*>(&wh[(r0 + 2) * 132 + o0]) = acc2;
    *reinterpret_cast<f32x4*>(&wh[(r0 + 3) * 132 + o0]) = acc3;
    __syncthreads();

    {
        int o = t & 127, rg2 = t >> 7;
        short8 lo, hi;
        #pragma unroll
        for (int r = 0; r < 8; r++) lo[r] = f2bf(wh[(rg2 * 16 + r) * 132 + o]);
        #pragma unroll
        for (int r = 0; r < 8; r++) hi[r] = f2bf(wh[(rg2 * 16 + 8 + r) * 132 + o]);
        size_t base = ((size_t)(b * 128 + o)) * 2048 + n0 + rg2 * 16;
        *reinterpret_cast<short8*>(whT + base)     = lo;
        *reinterpret_cast<short8*>(whT + base + 8) = hi;
    }

    {
        int r = t & 31, og8 = t >> 5;
        float s1 = 0.f, s2 = 0.f;
        #pragma unroll
        for (int k = 0; k < 16; k++) {
            float v = wh[r * 132 + og8 * 16 + k];
            s1 += v * av[og8 * 16 + k];
            s2 += v * av[128 + og8 * 16 + k];
        }
        plds[(r * 8 + og8) * 2 + 0] = s1;
        plds[(r * 8 + og8) * 2 + 1] = s2;
    }
    __syncthreads();
    if (t < 64) {
        int r = t & 31, which = t >> 5;
        float s = 0.f;
        #pragma unroll
        for (int og8 = 0; og8 < 8; og8++) s += plds[(r * 8 + og8) * 2 + which];
        if (which == 0) f1g[b * 2048 + n0 + r] = s;
        else            f2g[b * 2048 + n0 + r] = s;
    }
}

// ---------------- Kernel G2: fused E=exp(lrelu(f1+f2))*mask, O=E@Wh^T, out=elu(O/l+bias) ----
// grid 512: (b, 32i-tile). BK=32, 4-deep B-ring, prefetch distance 3, ONE barrier per iter.
__global__ __launch_bounds__(256) void kG2(const uint32_t* __restrict__ maskg,
                                           const short* __restrict__ whT,
                                           const float* __restrict__ f1g,
                                           const float* __restrict__ f2g,
                                           const float* __restrict__ bias,
                                           float* __restrict__ out) {
    int blk = blockIdx.x;
    int b      = blk >> 6;
    int i_tile = (blk & 63) * 32;
    int t = threadIdx.x;
    int w = t >> 6, lane = t & 63, il = lane & 15, quad = lane >> 4;
    int ihalf = w & 1, ohalf = w >> 1;
    int i_base = i_tile + ihalf * 16;
    int ow = ohalf * 64;

    __shared__ uint32_t m32l[32 * 68];   // stride 68: 2-way conflict max (free, m136)
    __shared__ float    f2l[2048];
    __shared__ short    Bl[4][128 * 32]; // 32 KB ring
    __shared__ float    lred[32 * 4];
    __shared__ float    linvl[32];

    // extras first (oldest in vmcnt queue; their ds_writes force their drain pre-loop)
    const uint4* msrc = reinterpret_cast<const uint4*>(maskg + (size_t)i_tile * 64);
    uint4 mv0 = msrc[t];
    uint4 mv1 = msrc[t + 256];
    const f32x4* fsrc = reinterpret_cast<const f32x4*>(f2g + b * 2048);
    f32x4 fv0 = fsrc[t];
    f32x4 fv1 = fsrc[t + 256];
    float f1v = f1g[b * 2048 + i_base + il];

    {
        int row0 = t >> 4, wq0 = (t & 15) * 4;
        *reinterpret_cast<uint4*>(&m32l[row0 * 68 + wq0]) = mv0;
        int idx = t + 256;
        int row1 = idx >> 4, wq1 = (idx & 15) * 4;
        *reinterpret_cast<uint4*>(&m32l[row1 * 68 + wq1]) = mv1;
        f32x4* fdst = reinterpret_cast<f32x4*>(f2l);
        fdst[t]       = fv0;
        fdst[t + 256] = fv1;
    }

    // B staging geometry (swizzled, verified R3/R4)
    int r = t >> 2, cs = t & 3;
    int rB1 = r + 64;
    const short* gB0 = whT + ((size_t)(b * 128 + r))   * 2048 + ((cs ^ ((r   >> 1) & 3)) << 3);
    const short* gB1 = whT + ((size_t)(b * 128 + rB1)) * 2048 + ((cs ^ ((rB1 >> 1) & 3)) << 3);
    int lslot = t * 8;

    // prologue: stage tiles 0,1,2 into bufs 0,1,2
    #pragma unroll
    for (int p = 0; p < 3; p++) {
        gload16(gB0 + p * 32, &Bl[p][lslot]);
        gload16(gB1 + p * 32, &Bl[p][2048 + lslot]);
    }

    int sw = (quad ^ ((il >> 1) & 3)) << 3;
    int offB0 = (ow + 0  + il) * 32 + sw;
    int offB1 = (ow + 16 + il) * 32 + sw;
    int offB2 = (ow + 32 + il) * 32 + sw;
    int offB3 = (ow + 48 + il) * 32 + sw;
    int mrow = (ihalf * 16 + il) * 68;

    f32x4 acc0 = {0.f,0.f,0.f,0.f}, acc1 = {0.f,0.f,0.f,0.f};
    f32x4 acc2 = {0.f,0.f,0.f,0.f}, acc3 = {0.f,0.f,0.f,0.f};
    float lpart = 0.f;

    // barrier covering mask/f2 LDS stores; leaves ring gloads in flight (lgkm only)
    __asm__ __volatile__("" ::: "memory");
    __builtin_amdgcn_s_waitcnt(0xC07F);   // lgkmcnt(0)
    __builtin_amdgcn_s_barrier();
    __asm__ __volatile__("" ::: "memory");

#define KSTEP(KB, CUR, WAITN, STAGE) do {                                        \
    __asm__ __volatile__("" ::: "memory");                                       \
    __builtin_amdgcn_s_waitcnt(0x0F70 | (WAITN));  /* vmcnt(WAITN) */            \
    __builtin_amdgcn_s_barrier();                                                \
    __asm__ __volatile__("" ::: "memory");                                       \
    if (STAGE) {                                                                 \
        int ko = ((KB) + 3) * 32;                                                \
        gload16(gB0 + ko, &Bl[((KB) + 3) & 3][lslot]);                           \
        gload16(gB1 + ko, &Bl[((KB) + 3) & 3][2048 + lslot]);                    \
    }                                                                            \
    uint32_t mw = m32l[mrow + (KB)];                                             \
    f32x4 q0 = *reinterpret_cast<const f32x4*>(&f2l[(KB) * 32 + quad * 8]);      \
    f32x4 q1 = *reinterpret_cast<const f32x4*>(&f2l[(KB) * 32 + quad * 8 + 4]);  \
    short8 af; float esum = 0.f;                                                 \
    _Pragma("unroll")                                                            \
    for (int k = 0; k < 8; k++) {                                                \
        float qv = (k < 4) ? q0[k] : q1[k - 4];                                  \
        float x = f1v + qv;                                                      \
        x = fmaxf(x, ALPHA * x);                                                 \
        float e = ((mw >> (quad * 8 + k)) & 1u) ? __expf(x) : 0.f;               \
        af[k] = f2bf(e); esum += e;                                              \
    }                                                                            \
    lpart += esum;                                                               \
    const short* Bb = &Bl[CUR][0];                                               \
    short8 b0 = *reinterpret_cast<const short8*>(Bb + offB0);                    \
    short8 b1 = *reinterpret_cast<const short8*>(Bb + offB1);                    \
    short8 b2 = *reinterpret_cast<const short8*>(Bb + offB2);                    \
    short8 b3 = *reinterpret_cast<const short8*>(Bb + offB3);                    \
    acc0 = __builtin_amdgcn_mfma_f32_16x16x32_bf16(af, b0, acc0, 0, 0, 0);       \
    acc1 = __builtin_amdgcn_mfma_f32_16x16x32_bf16(af, b1, acc1, 0, 0, 0);       \
    acc2 = __builtin_amdgcn_mfma_f32_16x16x32_bf16(af, b2, acc2, 0, 0, 0);       \
    acc3 = __builtin_amdgcn_mfma_f32_16x16x32_bf16(af, b3, acc3, 0, 0, 0);       \
} while (0)

    for (int kbo = 0; kbo < 60; kbo += 4) {
        KSTEP(kbo + 0, 0, 4, 1);
        KSTEP(kbo + 1, 1, 4, 1);
        KSTEP(kbo + 2, 2, 4, 1);
        KSTEP(kbo + 3, 3, 4, 1);
    }
    KSTEP(60, 0, 4, 1);
    KSTEP(61, 1, 4, 0);
    KSTEP(62, 2, 2, 0);
    KSTEP(63, 3, 0, 0);
#undef KSTEP

    if (ohalf == 0) lred[(ihalf * 16 + il) * 4 + quad] = lpart;
    __syncthreads();
    if (t < 32) {
        float l = lred[t * 4] + lred[t * 4 + 1] + lred[t * 4 + 2] + lred[t * 4 + 3];
        linvl[t] = 1.f / l;
    }
    __syncthreads();

    f32x4 accs[4] = {acc0, acc1, acc2, acc3};
    #pragma unroll
    for (int t4 = 0; t4 < 4; t4++) {
        int oo = ow + t4 * 16 + il;
        float bv = bias[oo];
        #pragma unroll
        for (int rr = 0; rr < 4; rr++) {
            int irel = ihalf * 16 + quad * 4 + rr;
            float v = accs[t4][rr] * linvl[irel] + bv;
            int ii = i_tile + irel;
            out[((size_t)(b * 2048 + ii)) * 128 + oo] = v > 0.f ? v : (__expf(v) - 1.f);
        }
    }
}

extern "C" void kernel_launch(void* const* d_in, const int* in_sizes, int n_in,
                              void* d_out, int out_size, void* d_ws, size_t ws_size,
                              hipStream_t stream) {
    const float* h    = (const float*)d_in[0];
    const float* adj  = (const float*)d_in[1];
    const float* W    = (const float*)d_in[2];
    const float* av   = (const float*)d_in[3];
    const float* bias = (const float*)d_in[4];
    float* out = (float*)d_out;

    char* ws = (char*)d_ws;
    short*    whT   = (short*)ws;                       // 4 MB
    float*    f1g   = (float*)(ws + (4 << 20));         // 64 KB
    float*    f2g   = f1g + 16384;                      // 64 KB
    uint32_t* maskg = (uint32_t*)(ws + (5 << 20));      // 512 KB

    kA<<<512, 256, 0, stream>>>(h, W, av, adj, whT, f1g, f2g, maskg);
    kG2<<<512, 256, 0, stream>>>(maskg, whT, f1g, f2g, bias, out);
}